// Round 5
// baseline (561.330 us; speedup 1.0000x reference)
//
#include <hip/hip_runtime.h>
#include <hip/hip_bf16.h>

#define NB 8
#define NG 8
#define NT 4096
#define NDIM 1024
#define NGD 128
#define NATT 128
#define NKL 256
#define FSCALE 0.08838834764831845f  // 1/sqrt(128)

typedef __bf16 bf16x8 __attribute__((ext_vector_type(8)));
typedef float f32x4 __attribute__((ext_vector_type(4)));
typedef ushort u16x8 __attribute__((ext_vector_type(8)));
typedef ushort u16x4 __attribute__((ext_vector_type(4)));

#define MFMA(a, b, c) __builtin_amdgcn_mfma_f32_16x16x32_bf16(a, b, c, 0, 0, 0)

__device__ __forceinline__ ushort f2bf(float f) {  // RNE
  union { float f; unsigned u; } v; v.f = f;
  unsigned r = v.u + 0x7FFFu + ((v.u >> 16) & 1u);
  return (ushort)(r >> 16);
}

__device__ __forceinline__ void gload16(const ushort* g, ushort* l) {
  __builtin_amdgcn_global_load_lds(
      (const __attribute__((address_space(1))) unsigned int*)g,
      (__attribute__((address_space(3))) unsigned int*)l, 16, 0, 0);
}

// ---------------------------------------------------------------------------
// K0: sel=0: WvoT[f][d] = sum_e Wv[d][e]*Wo[e][f]
//     sel=1: WkQT[e][d] = SCALE * sum_a Wk[d][a]*Wq[e][a]
// Both operands staged in LDS; pure-LDS fp32 inner loop. ~8 us.
// ---------------------------------------------------------------------------
__global__ __launch_bounds__(512) void k0_weights(
    const float* __restrict__ Wq, const float* __restrict__ Wk,
    const float* __restrict__ Wv, const float* __restrict__ Wo,
    ushort* __restrict__ WkQT, ushort* __restrict__ WvoT) {
  const int sel = blockIdx.x;
  const int g = blockIdx.y;
  __shared__ float A2[128 * 136];
  __shared__ float B2[128 * 136];
  const int tid = threadIdx.x;

  if (sel == 0) {
#pragma unroll
    for (int u = 0; u < 8; ++u) {
      const int c = tid + 512 * u;
      const int row = c >> 5, c4 = (c & 31) * 4;
      *(float4*)&A2[row * 136 + c4] =
          *(const float4*)&Wo[(size_t)g * 16384 + row * 128 + c4];
      const float4 v = *(const float4*)&Wv[(size_t)g * 16384 + row * 128 + c4];
      B2[(c4 + 0) * 136 + row] = v.x;
      B2[(c4 + 1) * 136 + row] = v.y;
      B2[(c4 + 2) * 136 + row] = v.z;
      B2[(c4 + 3) * 136 + row] = v.w;
    }
  } else {
#pragma unroll
    for (int u = 0; u < 8; ++u) {
      const int c = tid + 512 * u;
      const int row = c >> 5, c4 = (c & 31) * 4;
      const float4 q = *(const float4*)&Wq[(size_t)g * 16384 + row * 128 + c4];
      A2[(c4 + 0) * 136 + row] = q.x;
      A2[(c4 + 1) * 136 + row] = q.y;
      A2[(c4 + 2) * 136 + row] = q.z;
      A2[(c4 + 3) * 136 + row] = q.w;
      const float4 k = *(const float4*)&Wk[(size_t)g * 16384 + row * 128 + c4];
      B2[(c4 + 0) * 136 + row] = k.x;
      B2[(c4 + 1) * 136 + row] = k.y;
      B2[(c4 + 2) * 136 + row] = k.z;
      B2[(c4 + 3) * 136 + row] = k.w;
    }
  }
  __syncthreads();

  const int mr = tid >> 4;
  const int mc = tid & 15;
  float acc[4][8];
#pragma unroll
  for (int i = 0; i < 4; ++i)
#pragma unroll
    for (int j = 0; j < 8; ++j) acc[i][j] = 0.f;

#pragma unroll 4
  for (int k = 0; k < 128; ++k) {
    const float4 a = *(const float4*)&A2[k * 136 + mr * 4];
    const float4 b0 = *(const float4*)&B2[k * 136 + mc * 8];
    const float4 b1 = *(const float4*)&B2[k * 136 + mc * 8 + 4];
    const float av[4] = {a.x, a.y, a.z, a.w};
    const float bv[8] = {b0.x, b0.y, b0.z, b0.w, b1.x, b1.y, b1.z, b1.w};
#pragma unroll
    for (int i = 0; i < 4; ++i)
#pragma unroll
      for (int j = 0; j < 8; ++j) acc[i][j] += av[i] * bv[j];
  }

  const float sc = sel ? FSCALE : 1.f;
  ushort* dst = (sel ? WkQT : WvoT) + (size_t)g * 16384;
#pragma unroll
  for (int i = 0; i < 4; ++i) {
    u16x8 pk;
#pragma unroll
    for (int j = 0; j < 8; ++j) pk[j] = f2bf(acc[i][j] * sc);
    *(u16x8*)&dst[(size_t)(mr * 4 + i) * 128 + mc * 8] = pk;
  }
}

// ---------------------------------------------------------------------------
// KT_X: xT[bg][d][t] bf16 from x[b][t][g*128+d] fp32. grid (64 tc, 64 bg).
// 8 consecutive lanes write one 128B d-row segment (coalesced).
// ---------------------------------------------------------------------------
__global__ __launch_bounds__(256) void kt_x(const float* __restrict__ x,
                                            ushort* __restrict__ xT) {
  const int t0 = blockIdx.x * 64;
  const int bg = blockIdx.y;
  const int b = bg >> 3, g = bg & 7;
  __shared__ float xl[64 * 132];
#pragma unroll
  for (int u = 0; u < 8; ++u) {
    const int c = threadIdx.x + 256 * u;
    const int row = c >> 5, c4 = (c & 31) * 4;
    *(float4*)&xl[row * 132 + c4] =
        *(const float4*)&x[((size_t)b * NT + t0 + row) * NDIM + g * 128 + c4];
  }
  __syncthreads();
  const int seg = threadIdx.x & 7;
  const int d0 = threadIdx.x >> 3;
#pragma unroll
  for (int u = 0; u < 4; ++u) {
    const int d = d0 + u * 32;
    u16x8 pk;
#pragma unroll
    for (int z = 0; z < 8; ++z) pk[z] = f2bf(xl[(seg * 8 + z) * 132 + d]);
    *(u16x8*)&xT[((size_t)bg * 128 + d) * NT + t0 + seg * 8] = pk;
  }
}

// ---------------------------------------------------------------------------
// KT_P: PT[g][kl][t] bf16 from P[g][t][kl]. grid (64 tc, 2 klh, 8 g).
// ---------------------------------------------------------------------------
__global__ __launch_bounds__(256) void kt_p(const float* __restrict__ P,
                                            ushort* __restrict__ PT) {
  const int t0 = blockIdx.x * 64;
  const int klh = blockIdx.y, g = blockIdx.z;
  __shared__ float pl[64 * 132];
#pragma unroll
  for (int u = 0; u < 8; ++u) {
    const int c = threadIdx.x + 256 * u;
    const int row = c >> 5, c4 = (c & 31) * 4;
    *(float4*)&pl[row * 132 + c4] =
        *(const float4*)&P[((size_t)g * NT + t0 + row) * NKL + klh * 128 + c4];
  }
  __syncthreads();
  const int seg = threadIdx.x & 7;
  const int k0 = threadIdx.x >> 3;
#pragma unroll
  for (int u = 0; u < 4; ++u) {
    const int kl = k0 + u * 32;
    u16x8 pk;
#pragma unroll
    for (int z = 0; z < 8; ++z) pk[z] = f2bf(pl[(seg * 8 + z) * 132 + kl]);
    *(u16x8*)&PT[((size_t)g * NKL + klh * 128 + kl) * NT + t0 + seg * 8] = pk;
  }
}

// ---------------------------------------------------------------------------
// K1: C1 = P^T@X (128kl x 128d, K=4096, BK=32, global_load_lds dbuf, XOR
// swizzle), epilogue C2 = C1@W. 1-D grid 256, XCD-cluster swizzle so the 4
// blocks sharing xT[bg] co-reside on one XCD (xT from L2, not HBM 4x).
// ---------------------------------------------------------------------------
__global__ __launch_bounds__(256, 2) void k1_mfma(
    const ushort* __restrict__ PkT, const ushort* __restrict__ PvT,
    const ushort* __restrict__ xT, const ushort* __restrict__ WkQT,
    const ushort* __restrict__ WvoT, ushort* __restrict__ MQ,
    ushort* __restrict__ vo_redT) {
  const int bid = blockIdx.x;
  const int work = (bid & 7) * 32 + (bid >> 3);  // cluster 8 bg per XCD
  const int bg = work >> 2;
  const int sel = (work >> 1) & 1;
  const int klt = work & 1;
  const int g = bg & 7;
  const ushort* PT = (sel ? PvT : PkT) + ((size_t)g * NKL + klt * 128) * NT;
  const ushort* Xb = xT + (size_t)bg * 128 * NT;

  __shared__ ushort lds[17408];

  const int tid = threadIdx.x;
  const int w = tid >> 6, lane = tid & 63;
  const int l15 = lane & 15, l4 = lane >> 4;
  const int rh = (w & 1) * 64;
  const int ch = (w >> 1) * 64;
  const int srow = lane >> 2, sc = lane & 3;

  f32x4 acc[4][4];
  const f32x4 fz = {0.f, 0.f, 0.f, 0.f};
#pragma unroll
  for (int i = 0; i < 4; ++i)
#pragma unroll
    for (int j = 0; j < 4; ++j) acc[i][j] = fz;

#define K1_STAGE(buf, s)                                                     \
  {                                                                          \
    const int t0_ = (s) * 32;                                                \
    ushort* Ab_ = &lds[(buf) * 8192];                                        \
    ushort* Bb_ = &lds[(buf) * 8192 + 4096];                                 \
    _Pragma("unroll") for (int u = 0; u < 2; ++u) {                          \
      const int row_ = w * 32 + u * 16 + srow;                               \
      const size_t off_ = (size_t)row_ * NT + t0_ + ((sc ^ (row_ & 3)) << 3);\
      gload16(PT + off_, Ab_ + (w * 32 + u * 16) * 32);                      \
      gload16(Xb + off_, Bb_ + (w * 32 + u * 16) * 32);                      \
    }                                                                        \
  }

#define K1_COMPUTE(buf)                                                      \
  {                                                                          \
    const ushort* Ab_ = &lds[(buf) * 8192];                                  \
    const ushort* Bb_ = &lds[(buf) * 8192 + 4096];                           \
    bf16x8 af_[4], bf_[4];                                                   \
    _Pragma("unroll") for (int i = 0; i < 4; ++i) {                          \
      const int row_ = rh + i * 16 + l15;                                    \
      af_[i] = *(const bf16x8*)&Ab_[row_ * 32 + ((l4 ^ (row_ & 3)) << 3)];   \
    }                                                                        \
    _Pragma("unroll") for (int j = 0; j < 4; ++j) {                          \
      const int row_ = ch + j * 16 + l15;                                    \
      bf_[j] = *(const bf16x8*)&Bb_[row_ * 32 + ((l4 ^ (row_ & 3)) << 3)];   \
    }                                                                        \
    _Pragma("unroll") for (int i = 0; i < 4; ++i)                            \
      _Pragma("unroll") for (int j = 0; j < 4; ++j)                          \
        acc[i][j] = MFMA(af_[i], bf_[j], acc[i][j]);                         \
  }

  K1_STAGE(0, 0);
  __syncthreads();
  int buf = 0;
#pragma unroll 1
  for (int s = 0; s < 128; ++s) {
    if (s + 1 < 128) K1_STAGE(buf ^ 1, s + 1);
    K1_COMPUTE(buf);
    __syncthreads();
    buf ^= 1;
  }

  ushort* C = lds;
#pragma unroll
  for (int i = 0; i < 4; ++i)
#pragma unroll
    for (int j = 0; j < 4; ++j)
#pragma unroll
      for (int r = 0; r < 4; ++r)
        C[(rh + i * 16 + l4 * 4 + r) * 136 + ch + j * 16 + l15] =
            f2bf(acc[i][j][r]);
  __syncthreads();

  const ushort* WT = (sel ? WvoT : WkQT) + (size_t)g * 16384;
  f32x4 o[4][4];
#pragma unroll
  for (int i = 0; i < 4; ++i)
#pragma unroll
    for (int j = 0; j < 4; ++j) o[i][j] = fz;
#pragma unroll
  for (int ks = 0; ks < 4; ++ks) {
    bf16x8 af[4], bfr[4];
#pragma unroll
    for (int i = 0; i < 4; ++i)
      af[i] = *(const bf16x8*)&C[(rh + i * 16 + l15) * 136 + ks * 32 + l4 * 8];
#pragma unroll
    for (int j = 0; j < 4; ++j)
      bfr[j] = *(const bf16x8*)&WT[(size_t)(ch + j * 16 + l15) * 128 + ks * 32 + l4 * 8];
#pragma unroll
    for (int i = 0; i < 4; ++i)
#pragma unroll
      for (int j = 0; j < 4; ++j) o[i][j] = MFMA(af[i], bfr[j], o[i][j]);
  }

  if (sel == 0) {
#pragma unroll
    for (int i = 0; i < 4; ++i)
#pragma unroll
      for (int j = 0; j < 4; ++j)
#pragma unroll
        for (int r = 0; r < 4; ++r)
          MQ[((size_t)bg * NKL + klt * 128 + rh + i * 16 + l4 * 4 + r) * 128 +
             ch + j * 16 + l15] = f2bf(o[i][j][r]);
  } else {
#pragma unroll
    for (int i = 0; i < 4; ++i)
#pragma unroll
      for (int j = 0; j < 4; ++j) {
        u16x4 pk;
#pragma unroll
        for (int r = 0; r < 4; ++r) pk[r] = f2bf(o[i][j][r]);
        *(u16x4*)&vo_redT[((size_t)bg * 128 + ch + j * 16 + l15) * NKL +
                          klt * 128 + rh + i * 16 + l4 * 4] = pk;
      }
  }
}

// ---------------------------------------------------------------------------
// K2: barrier-free fused attention. Swapped QK^T (S^T = MQ @ x^T) makes each
// lane own full kl for one t-row -> in-lane softmax + 2 shfl_xor. Per wave:
// 32 t-rows/step, att LDS private per wave (no __syncthreads in main loop).
// mq frag reused 2x, vo frag reused 2x. grid (4, 64), 512 thr, 136 KB LDS.
// ---------------------------------------------------------------------------
__global__ __launch_bounds__(512) void k2_attn(
    const float* __restrict__ x, const ushort* __restrict__ MQ,
    const ushort* __restrict__ vo_redT, float* __restrict__ out) {
  const int tc = blockIdx.x;  // 0..3, 1024 t-rows each
  const int bg = blockIdx.y;
  const int b = bg >> 3, g = bg & 7;

  __shared__ ushort mq[256 * 136];      // 69632 B
  __shared__ ushort att[8 * 16 * 272];  // 69632 B, per-wave [16][272]

  const int tid = threadIdx.x;
  const int w = tid >> 6, lane = tid & 63;
  const int l15 = lane & 15, l4 = lane >> 4;
  ushort* attw = att + w * 16 * 272;
  const f32x4 fz = {0.f, 0.f, 0.f, 0.f};

  const float* xb = x + ((size_t)b * NT + tc * 1024) * NDIM + g * 128;
  const ushort* vo = vo_redT + (size_t)bg * 128 * NKL;

  // prologue: x loads for step 0 (overlap with mq staging)
  float4 xr[16];
#pragma unroll
  for (int rt = 0; rt < 2; ++rt)
#pragma unroll
    for (int ks = 0; ks < 4; ++ks) {
      const float* p = xb + (size_t)(w * 32 + rt * 16 + l15) * NDIM + ks * 32 + l4 * 8;
      xr[rt * 8 + ks * 2] = *(const float4*)p;
      xr[rt * 8 + ks * 2 + 1] = *(const float4*)(p + 4);
    }

  {  // stage mq once
    const ushort* src = MQ + (size_t)bg * NKL * 128;
#pragma unroll
    for (int u = 0; u < 8; ++u) {
      const int c = tid + 512 * u;
      const int r = c >> 4, c8 = (c & 15) * 8;
      *(u16x8*)&mq[r * 136 + c8] = *(const u16x8*)&src[r * 128 + c8];
    }
  }
  __syncthreads();  // the only block-wide barrier

#pragma unroll 1
  for (int st = 0; st < 4; ++st) {
    // convert current x to bf16 A-operands (B-side of swapped MFMA)
    bf16x8 a0[4], a1[4];
#pragma unroll
    for (int ks = 0; ks < 4; ++ks) {
      bf16x8 t0, t1;
      const float4 u0 = xr[ks * 2], u1 = xr[ks * 2 + 1];
      const float4 v0 = xr[8 + ks * 2], v1 = xr[8 + ks * 2 + 1];
      t0[0] = (__bf16)u0.x; t0[1] = (__bf16)u0.y; t0[2] = (__bf16)u0.z; t0[3] = (__bf16)u0.w;
      t0[4] = (__bf16)u1.x; t0[5] = (__bf16)u1.y; t0[6] = (__bf16)u1.z; t0[7] = (__bf16)u1.w;
      t1[0] = (__bf16)v0.x; t1[1] = (__bf16)v0.y; t1[2] = (__bf16)v0.z; t1[3] = (__bf16)v0.w;
      t1[4] = (__bf16)v1.x; t1[5] = (__bf16)v1.y; t1[6] = (__bf16)v1.z; t1[7] = (__bf16)v1.w;
      a0[ks] = t0; a1[ks] = t1;
    }

    // S^T = MQ @ x^T : lane -> S[t=l15][kl = n*16 + l4*4 + r]
    f32x4 s0[16], s1[16];
#pragma unroll
    for (int n = 0; n < 16; ++n) { s0[n] = fz; s1[n] = fz; }
#pragma unroll
    for (int ks = 0; ks < 4; ++ks)
#pragma unroll
      for (int n = 0; n < 16; ++n) {
        const bf16x8 mf = *(const bf16x8*)&mq[(n * 16 + l15) * 136 + ks * 32 + l4 * 8];
        s0[n] = MFMA(mf, a0[ks], s0[n]);
        s1[n] = MFMA(mf, a1[ks], s1[n]);
      }

    // wave-local softmax (in-lane 64 values + shfl_xor 16,32)
    float inv0, inv1;
    {
      f32x4 m4 = s0[0];
#pragma unroll
      for (int n = 1; n < 16; ++n)
#pragma unroll
        for (int r = 0; r < 4; ++r) m4[r] = fmaxf(m4[r], s0[n][r]);
      float m = fmaxf(fmaxf(m4[0], m4[1]), fmaxf(m4[2], m4[3]));
      m = fmaxf(m, __shfl_xor(m, 16, 64));
      m = fmaxf(m, __shfl_xor(m, 32, 64));
      f32x4 sum4 = fz;
#pragma unroll
      for (int n = 0; n < 16; ++n)
#pragma unroll
        for (int r = 0; r < 4; ++r) {
          const float p = __expf(s0[n][r] - m);
          s0[n][r] = p;
          sum4[r] += p;
        }
      float sm = (sum4[0] + sum4[1]) + (sum4[2] + sum4[3]);
      sm += __shfl_xor(sm, 16, 64);
      sm += __shfl_xor(sm, 32, 64);
      inv0 = 1.f / sm;
    }
    {
      f32x4 m4 = s1[0];
#pragma unroll
      for (int n = 1; n < 16; ++n)
#pragma unroll
        for (int r = 0; r < 4; ++r) m4[r] = fmaxf(m4[r], s1[n][r]);
      float m = fmaxf(fmaxf(m4[0], m4[1]), fmaxf(m4[2], m4[3]));
      m = fmaxf(m, __shfl_xor(m, 16, 64));
      m = fmaxf(m, __shfl_xor(m, 32, 64));
      f32x4 sum4 = fz;
#pragma unroll
      for (int n = 0; n < 16; ++n)
#pragma unroll
        for (int r = 0; r < 4; ++r) {
          const float p = __expf(s1[n][r] - m);
          s1[n][r] = p;
          sum4[r] += p;
        }
      float sm = (sum4[0] + sum4[1]) + (sum4[2] + sum4[3]);
      sm += __shfl_xor(sm, 16, 64);
      sm += __shfl_xor(sm, 32, 64);
      inv1 = 1.f / sm;
    }

    // att roundtrip per row-tile (wave-private region; DS in-order per wave)
    bf16x8 attf0[8], attf1[8];
#pragma unroll
    for (int n = 0; n < 16; ++n) {
      u16x4 pk;
#pragma unroll
      for (int r = 0; r < 4; ++r) pk[r] = f2bf(s0[n][r] * inv0);
      *(u16x4*)&attw[l15 * 272 + n * 16 + l4 * 4] = pk;
    }
#pragma unroll
    for (int ks = 0; ks < 8; ++ks)
      attf0[ks] = *(const bf16x8*)&attw[l15 * 272 + ks * 32 + l4 * 8];
#pragma unroll
    for (int n = 0; n < 16; ++n) {
      u16x4 pk;
#pragma unroll
      for (int r = 0; r < 4; ++r) pk[r] = f2bf(s1[n][r] * inv1);
      *(u16x4*)&attw[l15 * 272 + n * 16 + l4 * 4] = pk;
    }
#pragma unroll
    for (int ks = 0; ks < 8; ++ks)
      attf1[ks] = *(const bf16x8*)&attw[l15 * 272 + ks * 32 + l4 * 8];

    // prefetch next step's x while PV runs
    if (st < 3) {
      const float* pn = xb + (size_t)((st + 1) * 256 + w * 32) * NDIM;
#pragma unroll
      for (int rt = 0; rt < 2; ++rt)
#pragma unroll
        for (int ks = 0; ks < 4; ++ks) {
          const float* p = pn + (size_t)(rt * 16 + l15) * NDIM + ks * 32 + l4 * 8;
          xr[rt * 8 + ks * 2] = *(const float4*)p;
          xr[rt * 8 + ks * 2 + 1] = *(const float4*)(p + 4);
        }
    }

    // PV: O = att @ vo^T, vo frags from L2, each reused for both row-tiles
    f32x4 oa0[8], oa1[8];
#pragma unroll
    for (int dt = 0; dt < 8; ++dt) { oa0[dt] = fz; oa1[dt] = fz; }
#pragma unroll
    for (int ks = 0; ks < 8; ++ks)
#pragma unroll
      for (int dt = 0; dt < 8; ++dt) {
        const bf16x8 vf =
            *(const bf16x8*)&vo[(size_t)(dt * 16 + l15) * NKL + ks * 32 + l4 * 8];
        oa0[dt] = MFMA(attf0[ks], vf, oa0[dt]);
        oa1[dt] = MFMA(attf1[ks], vf, oa1[dt]);
      }

    float* ob = out + ((size_t)b * NT + tc * 1024 + st * 256 + w * 32) * NDIM + g * 128;
#pragma unroll
    for (int dt = 0; dt < 8; ++dt)
#pragma unroll
      for (int r = 0; r < 4; ++r) {
        ob[(size_t)(l4 * 4 + r) * NDIM + dt * 16 + l15] = oa0[dt][r];
        ob[(size_t)(16 + l4 * 4 + r) * NDIM + dt * 16 + l15] = oa1[dt][r];
      }
  }
}

// ---------------------------------------------------------------------------
extern "C" void kernel_launch(void* const* d_in, const int* in_sizes, int n_in,
                              void* d_out, int out_size, void* d_ws, size_t ws_size,
                              hipStream_t stream) {
  (void)in_sizes; (void)n_in; (void)out_size; (void)ws_size;
  const float* x  = (const float*)d_in[0];
  const float* Wq = (const float*)d_in[1];
  const float* Wk = (const float*)d_in[2];
  const float* Wv = (const float*)d_in[3];
  const float* Wo = (const float*)d_in[4];
  const float* Pk = (const float*)d_in[5];
  const float* Pv = (const float*)d_in[6];

  ushort* wsu = (ushort*)d_ws;
  ushort* PkT     = wsu;                   // 8*256*4096
  ushort* PvT     = PkT + 8388608;
  ushort* WkQT    = PvT + 8388608;         // 8*128*128
  ushort* WvoT    = WkQT + 131072;
  ushort* MQ      = WvoT + 131072;         // 64*256*128
  ushort* vo_redT = MQ + 2097152;          // 64*128*256
  ushort* xT = (ushort*)d_out;             // 67 MB scratch; k2 overwrites d_out

  k0_weights<<<dim3(2, NG), dim3(512), 0, stream>>>(Wq, Wk, Wv, Wo, WkQT, WvoT);
  kt_x<<<dim3(64, 64), dim3(256), 0, stream>>>(x, xT);
  kt_p<<<dim3(64, 2, 8), dim3(256), 0, stream>>>(Pk, PkT);
  kt_p<<<dim3(64, 2, 8), dim3(256), 0, stream>>>(Pv, PvT);
  k1_mfma<<<dim3(256), dim3(256), 0, stream>>>(PkT, PvT, xT, WkQT, WvoT,
                                               MQ, vo_redT);
  k2_attn<<<dim3(4, 64), dim3(512), 0, stream>>>(x, MQ, vo_redT, (float*)d_out);
}